// Round 3
// baseline (280.726 us; speedup 1.0000x reference)
//
#include <hip/hip_runtime.h>

// Fused MHA: qkv = x@Wqkv+b; attn per head; out = vals@Wout+b
// B=4, S=2048, D=1024, H=16, Hd=64. Internal compute bf16 MFMA + fp32 accum.
// Round 3: attn rewrite — XOR-swizzled LDS (conflict-free frag reads),
// 32 q-rows/wave (shared K/V frag passes), reg-cached V frags,
// setprio around MFMA, XCD-chunked block remap.

typedef short bf16x8 __attribute__((ext_vector_type(8)));
typedef short bf16x4 __attribute__((ext_vector_type(4)));
typedef float f32x4 __attribute__((ext_vector_type(4)));

#define DIMM 1024
#define NH 16
#define HD 64
#define SEQ 2048
#define NB 4
#define MTOT (NB * SEQ)  // 8192
#define SCQ 0.18033688f  // 0.125 * log2(e), folded into Q

__device__ __forceinline__ short f2bf(float f) {
  __bf16 h = (__bf16)f;
  return __builtin_bit_cast(short, h);
}

// ---------------- x fp32 -> bf16 ----------------
__global__ __launch_bounds__(256) void k_cvt(const float* __restrict__ in,
                                             short* __restrict__ out, int n8) {
  const int stride = gridDim.x * blockDim.x;
  for (int i = blockIdx.x * blockDim.x + threadIdx.x; i < n8; i += stride) {
    const float4* p = (const float4*)(in + (size_t)i * 8);
    float4 a = p[0], b = p[1];
    bf16x8 h;
    h[0] = f2bf(a.x); h[1] = f2bf(a.y); h[2] = f2bf(a.z); h[3] = f2bf(a.w);
    h[4] = f2bf(b.x); h[5] = f2bf(b.y); h[6] = f2bf(b.z); h[7] = f2bf(b.w);
    *(bf16x8*)(out + (size_t)i * 8) = h;
  }
}

// ---------------- transpose + fp32->bf16: out[n][k] = in[k][n] ----------------
__global__ void k_transpose(const float* __restrict__ in, short* __restrict__ out,
                            int K, int N) {
  __shared__ float tile[32][33];
  const int n0 = blockIdx.x * 32, k0 = blockIdx.y * 32;
  const int tx = threadIdx.x, ty = threadIdx.y;
#pragma unroll
  for (int i = 0; i < 32; i += 8)
    tile[ty + i][tx] = in[(size_t)(k0 + ty + i) * N + n0 + tx];
  __syncthreads();
#pragma unroll
  for (int i = 0; i < 32; i += 8)
    out[(size_t)(n0 + ty + i) * K + k0 + tx] = f2bf(tile[tx][ty + i]);
}

// ---------------- GEMM1: qkv = xb @ WqkvT^T + b; scatter Q(scaled)/K/V^T ----------------
__global__ __launch_bounds__(256) void k_gemm_qkv(
    const short* __restrict__ A, const short* __restrict__ Bt,
    const float* __restrict__ bias,
    short* __restrict__ qw, short* __restrict__ kw, short* __restrict__ vtg) {
  __shared__ alignas(16) short Als[128][40];
  __shared__ alignas(16) short Bls[128][40];
  const int tid = threadIdx.x, lane = tid & 63, wid = tid >> 6;
  const int wr = wid >> 1, wc = wid & 1;
  const int bm = blockIdx.x, bn = blockIdx.y;
  const int srow = tid >> 1, scb = (tid & 1) << 4;
  const int fr = lane & 15, fg = lane >> 4;
  f32x4 acc[4][4] = {};
  const short* Ap = A + (size_t)(bm * 128 + srow) * DIMM + scb;
  const short* Bp = Bt + (size_t)(bn * 128 + srow) * DIMM + scb;
  for (int k0 = 0; k0 < DIMM; k0 += 32) {
    __syncthreads();
    *(bf16x8*)&Als[srow][scb] = *(const bf16x8*)(Ap + k0);
    *(bf16x8*)&Als[srow][scb + 8] = *(const bf16x8*)(Ap + k0 + 8);
    *(bf16x8*)&Bls[srow][scb] = *(const bf16x8*)(Bp + k0);
    *(bf16x8*)&Bls[srow][scb + 8] = *(const bf16x8*)(Bp + k0 + 8);
    __syncthreads();
    bf16x8 af[4], bfv[4];
#pragma unroll
    for (int i = 0; i < 4; i++) {
      af[i] = *(const bf16x8*)&Als[wr * 64 + i * 16 + fr][fg * 8];
      bfv[i] = *(const bf16x8*)&Bls[wc * 64 + i * 16 + fr][fg * 8];
    }
#pragma unroll
    for (int i = 0; i < 4; i++)
#pragma unroll
      for (int j = 0; j < 4; j++)
        acc[i][j] = __builtin_amdgcn_mfma_f32_16x16x32_bf16(af[i], bfv[j], acc[i][j], 0, 0, 0);
  }
#pragma unroll
  for (int i = 0; i < 4; i++) {
    const int row0 = bm * 128 + wr * 64 + i * 16 + fg * 4;
    const int bb = row0 >> 11, s0 = row0 & 2047;
#pragma unroll
    for (int j = 0; j < 4; j++) {
      const int col = bn * 128 + wc * 64 + j * 16 + fr;
      const int h = col / 192;
      const int rem = col - h * 192;
      const int which = rem >> 6, d = rem & 63;
      const float bs = bias[col];
      if (which == 2) {
        bf16x4 pk;
#pragma unroll
        for (int r = 0; r < 4; r++) pk[r] = f2bf(acc[i][j][r] + bs);
        *(bf16x4*)&vtg[((size_t)((bb * NH + h) * HD + d)) * SEQ + s0] = pk;
      } else {
        short* dst = which == 0 ? qw : kw;
        const float scl = which == 0 ? SCQ : 1.f;
#pragma unroll
        for (int r = 0; r < 4; r++)
          dst[((size_t)((bb * NH + h) * SEQ + s0 + r)) * HD + d] =
              f2bf((acc[i][j][r] + bs) * scl);
      }
    }
  }
}

// ---------------- flash attention: swizzled LDS, 32 q-rows/wave ----------------
// Q pre-scaled by 0.125*log2e, so P = exp2(S - m) directly.
// LDS tiles [64][64] bf16 (128B rows); 16B slot s of row r lives at slot s^(r&7).
__global__ __launch_bounds__(256) void k_attn(
    const short* __restrict__ qw, const short* __restrict__ kw,
    const short* __restrict__ vt, short* __restrict__ vals) {
  __shared__ alignas(16) short Kls[64][64];
  __shared__ alignas(16) short Vls[64][64];          // [d][key]
  __shared__ alignas(16) short Pls[4][2][16][64];    // per-wave, per-group [q][key]
  const int tid = threadIdx.x, lane = tid & 63, w = tid >> 6;
  const int fr = lane & 15, fg = lane >> 4;
  const int sw = fr & 7;  // frag-read row swizzle (row ≡ fr mod 8 for all frag reads)

  // XCD-chunked remap: nwg=1024; XCD k gets contiguous work ids -> 8 heads/XCD
  const int flat = blockIdx.y * gridDim.x + blockIdx.x;
  const int wrk = (flat & 7) * 128 + (flat >> 3);
  const int qt = wrk & 15, bh = wrk >> 4;

  const short* Qp = qw + (size_t)bh * SEQ * HD;
  const short* Kp = kw + (size_t)bh * SEQ * HD;
  const short* Vtp = vt + (size_t)bh * HD * SEQ;

  const int q0 = qt * 128 + w * 32;
  bf16x8 qf[2][2];
#pragma unroll
  for (int g = 0; g < 2; g++) {
    const size_t qr = (size_t)(q0 + g * 16 + fr) * HD;
    qf[g][0] = *(const bf16x8*)&Qp[qr + fg * 8];
    qf[g][1] = *(const bf16x8*)&Qp[qr + 32 + fg * 8];
  }

  f32x4 o[2][4] = {};
  float m[2] = {-1e30f, -1e30f};
  float ln[2] = {0.f, 0.f};

  const int srow = tid >> 2, sc = tid & 3;   // staging: row, 32B-chunk
  const int ssw = srow & 7;
  const int sl0 = ((sc * 2) ^ ssw) << 3;     // swizzled short-offsets of the 2 slots
  const int sl1 = ((sc * 2 + 1) ^ ssw) << 3;

  for (int t = 0; t < SEQ / 64; t++) {
    const int kb = t * 64;
    __syncthreads();
    {
      const short* kg = &Kp[(size_t)(kb + srow) * HD + sc * 16];
      *(bf16x8*)&Kls[srow][sl0] = *(const bf16x8*)kg;
      *(bf16x8*)&Kls[srow][sl1] = *(const bf16x8*)(kg + 8);
      const short* vg = &Vtp[(size_t)srow * SEQ + kb + sc * 16];
      *(bf16x8*)&Vls[srow][sl0] = *(const bf16x8*)vg;
      *(bf16x8*)&Vls[srow][sl1] = *(const bf16x8*)(vg + 8);
    }
    __syncthreads();

    // S^T = K Q^T for both q-groups; lane holds q = fr, keys kt*16 + fg*4 + r
    f32x4 s[2][4];
    __builtin_amdgcn_s_setprio(1);
#pragma unroll
    for (int kt = 0; kt < 4; kt++) {
      const bf16x8 kf0 = *(const bf16x8*)&Kls[kt * 16 + fr][(fg ^ sw) << 3];
      const bf16x8 kf1 = *(const bf16x8*)&Kls[kt * 16 + fr][((4 + fg) ^ sw) << 3];
#pragma unroll
      for (int g = 0; g < 2; g++) {
        f32x4 z = {0.f, 0.f, 0.f, 0.f};
        z = __builtin_amdgcn_mfma_f32_16x16x32_bf16(kf0, qf[g][0], z, 0, 0, 0);
        s[g][kt] = __builtin_amdgcn_mfma_f32_16x16x32_bf16(kf1, qf[g][1], z, 0, 0, 0);
      }
    }
    __builtin_amdgcn_s_setprio(0);

    // V frags once, reused by both groups
    bf16x8 vf[2][4];
#pragma unroll
    for (int c = 0; c < 2; c++)
#pragma unroll
      for (int dt = 0; dt < 4; dt++)
        vf[c][dt] = *(const bf16x8*)&Vls[dt * 16 + fr][((c * 4 + fg) ^ sw) << 3];

#pragma unroll
    for (int g = 0; g < 2; g++) {
      float mx = fmaxf(fmaxf(s[g][0][0], s[g][0][1]), fmaxf(s[g][0][2], s[g][0][3]));
      mx = fmaxf(mx, fmaxf(fmaxf(s[g][1][0], s[g][1][1]), fmaxf(s[g][1][2], s[g][1][3])));
      mx = fmaxf(mx, fmaxf(fmaxf(s[g][2][0], s[g][2][1]), fmaxf(s[g][2][2], s[g][2][3])));
      mx = fmaxf(mx, fmaxf(fmaxf(s[g][3][0], s[g][3][1]), fmaxf(s[g][3][2], s[g][3][3])));
      mx = fmaxf(mx, __shfl_xor(mx, 16));
      mx = fmaxf(mx, __shfl_xor(mx, 32));

      if (__any(mx > m[g])) {
        const float mnew = fmaxf(m[g], mx);
        const float al = exp2f(m[g] - mnew);
        m[g] = mnew;
        ln[g] *= al;
#pragma unroll
        for (int r = 0; r < 4; r++) {
          const float ar = __shfl(al, fg * 4 + r);
          o[g][0][r] *= ar; o[g][1][r] *= ar; o[g][2][r] *= ar; o[g][3][r] *= ar;
        }
      }

      float ts = 0.f;
#pragma unroll
      for (int kt = 0; kt < 4; kt++) {
        bf16x4 pk;
#pragma unroll
        for (int r = 0; r < 4; r++) {
          const float p = exp2f(s[g][kt][r] - m[g]);
          ts += p;
          pk[r] = f2bf(p);
        }
        *(bf16x4*)&Pls[w][g][fr][(((kt * 2 + (fg >> 1)) ^ sw) << 3) + ((fg & 1) << 2)] = pk;
      }
      ln[g] += ts;

      __builtin_amdgcn_s_setprio(1);
#pragma unroll
      for (int c = 0; c < 2; c++) {
        const bf16x8 pa = *(const bf16x8*)&Pls[w][g][fr][((c * 4 + fg) ^ sw) << 3];
#pragma unroll
        for (int dt = 0; dt < 4; dt++)
          o[g][dt] = __builtin_amdgcn_mfma_f32_16x16x32_bf16(pa, vf[c][dt], o[g][dt], 0, 0, 0);
      }
      __builtin_amdgcn_s_setprio(0);
    }
  }

  const int b = bh >> 4, h = bh & 15;
#pragma unroll
  for (int g = 0; g < 2; g++) {
    float lt = ln[g];
    lt += __shfl_xor(lt, 16);
    lt += __shfl_xor(lt, 32);
    const float inv = 1.f / lt;
#pragma unroll
    for (int r = 0; r < 4; r++) {
      const float ir = __shfl(inv, fg * 4 + r);
      const int row = q0 + g * 16 + 4 * fg + r;
      const size_t base = ((size_t)(b * SEQ + row)) * DIMM + h * HD;
#pragma unroll
      for (int dt = 0; dt < 4; dt++)
        vals[base + dt * 16 + fr] = f2bf(o[g][dt][r] * ir);
    }
  }
}

// ---------------- GEMM2: out = vals @ WoutT^T + b (fp32 out) ----------------
__global__ __launch_bounds__(256) void k_gemm_out(
    const short* __restrict__ A, const short* __restrict__ Bt,
    const float* __restrict__ bias, float* __restrict__ out) {
  __shared__ alignas(16) short Als[128][40];
  __shared__ alignas(16) short Bls[128][40];
  const int tid = threadIdx.x, lane = tid & 63, wid = tid >> 6;
  const int wr = wid >> 1, wc = wid & 1;
  const int bm = blockIdx.x, bn = blockIdx.y;
  const int srow = tid >> 1, scb = (tid & 1) << 4;
  const int fr = lane & 15, fg = lane >> 4;
  f32x4 acc[4][4] = {};
  const short* Ap = A + (size_t)(bm * 128 + srow) * DIMM + scb;
  const short* Bp = Bt + (size_t)(bn * 128 + srow) * DIMM + scb;
  for (int k0 = 0; k0 < DIMM; k0 += 32) {
    __syncthreads();
    *(bf16x8*)&Als[srow][scb] = *(const bf16x8*)(Ap + k0);
    *(bf16x8*)&Als[srow][scb + 8] = *(const bf16x8*)(Ap + k0 + 8);
    *(bf16x8*)&Bls[srow][scb] = *(const bf16x8*)(Bp + k0);
    *(bf16x8*)&Bls[srow][scb + 8] = *(const bf16x8*)(Bp + k0 + 8);
    __syncthreads();
    bf16x8 af[4], bfv[4];
#pragma unroll
    for (int i = 0; i < 4; i++) {
      af[i] = *(const bf16x8*)&Als[wr * 64 + i * 16 + fr][fg * 8];
      bfv[i] = *(const bf16x8*)&Bls[wc * 64 + i * 16 + fr][fg * 8];
    }
#pragma unroll
    for (int i = 0; i < 4; i++)
#pragma unroll
      for (int j = 0; j < 4; j++)
        acc[i][j] = __builtin_amdgcn_mfma_f32_16x16x32_bf16(af[i], bfv[j], acc[i][j], 0, 0, 0);
  }
#pragma unroll
  for (int i = 0; i < 4; i++) {
    const int row0 = bm * 128 + wr * 64 + i * 16 + fg * 4;
#pragma unroll
    for (int j = 0; j < 4; j++) {
      const int col = bn * 128 + wc * 64 + j * 16 + fr;
      const float bs = bias[col];
#pragma unroll
      for (int r = 0; r < 4; r++)
        out[(size_t)(row0 + r) * DIMM + col] = acc[i][j][r] + bs;
    }
  }
}

extern "C" void kernel_launch(void* const* d_in, const int* in_sizes, int n_in,
                              void* d_out, int out_size, void* d_ws, size_t ws_size,
                              hipStream_t stream) {
  (void)in_sizes; (void)n_in; (void)out_size;
  const float* x = (const float*)d_in[0];
  const float* Wqkv = (const float*)d_in[1];
  const float* bqkv = (const float*)d_in[2];
  const float* Wout = (const float*)d_in[3];
  const float* bout = (const float*)d_in[4];
  float* out = (float*)d_out;

  char* ws = (char*)d_ws;
  const size_t sz_wq = (size_t)3 * DIMM * DIMM * 2;
  const size_t sz_wo = (size_t)DIMM * DIMM * 2;
  const size_t sz_m = (size_t)MTOT * DIMM * 2;
  const size_t off_wq = 0;
  const size_t off_wo = off_wq + sz_wq;
  const size_t off_q = off_wo + sz_wo;
  const size_t off_k = off_q + sz_m;
  const size_t off_vt = off_k + sz_m;
  const size_t off_vals = off_vt + sz_m;  // doubles as xb
  const size_t need = off_vals + sz_m;
  if (ws_size < need) return;

  short* WqT = (short*)(ws + off_wq);
  short* WoT = (short*)(ws + off_wo);
  short* qws = (short*)(ws + off_q);
  short* kws = (short*)(ws + off_k);
  short* vtg = (short*)(ws + off_vt);
  short* xb = (short*)(ws + off_vals);
  short* valsws = (short*)(ws + off_vals);

  k_cvt<<<2048, 256, 0, stream>>>(x, xb, MTOT * DIMM / 8);
  k_transpose<<<dim3(3 * DIMM / 32, DIMM / 32), dim3(32, 8), 0, stream>>>(Wqkv, WqT, DIMM, 3 * DIMM);
  k_transpose<<<dim3(DIMM / 32, DIMM / 32), dim3(32, 8), 0, stream>>>(Wout, WoT, DIMM, DIMM);
  k_gemm_qkv<<<dim3(MTOT / 128, 3 * DIMM / 128), 256, 0, stream>>>(xb, WqT, bqkv, qws, kws, vtg);
  k_attn<<<dim3(SEQ / 128, NB * NH), 256, 0, stream>>>(qws, kws, vtg, valsws);
  k_gemm_out<<<dim3(MTOT / 128, DIMM / 128), 256, 0, stream>>>(valsws, WoT, bout, out);
}

// Round 4
// 243.101 us; speedup vs baseline: 1.1548x; 1.1548x over previous
//
#include <hip/hip_runtime.h>

// Fused MHA: qkv = x@Wqkv+b; attn per head; out = vals@Wout+b
// B=4, S=2048, D=1024, H=16, Hd=64. Internal compute bf16 MFMA + fp32 accum.
// Round 4: attn = 8-wave blocks, dbuf K/V via global_load_lds (pre-swizzled src),
// 1 barrier/tile; GEMMs = m97 staging (global_load_lds w16, unpadded LDS).

typedef short bf16x8 __attribute__((ext_vector_type(8)));
typedef short bf16x4 __attribute__((ext_vector_type(4)));
typedef float f32x4 __attribute__((ext_vector_type(4)));

#define DIMM 1024
#define NH 16
#define HD 64
#define SEQ 2048
#define NB 4
#define MTOT (NB * SEQ)  // 8192
#define SCQ 0.18033688f  // 0.125 * log2(e), folded into Q

__device__ __forceinline__ short f2bf(float f) {
  __bf16 h = (__bf16)f;
  return __builtin_bit_cast(short, h);
}

__device__ __forceinline__ void gload16(const short* g, const short* l) {
  __builtin_amdgcn_global_load_lds(
      (const __attribute__((address_space(1))) unsigned int*)g,
      (__attribute__((address_space(3))) unsigned int*)l, 16, 0, 0);
}

// ---------------- x fp32 -> bf16 ----------------
__global__ __launch_bounds__(256) void k_cvt(const float* __restrict__ in,
                                             short* __restrict__ out, int n8) {
  const int stride = gridDim.x * blockDim.x;
  for (int i = blockIdx.x * blockDim.x + threadIdx.x; i < n8; i += stride) {
    const float4* p = (const float4*)(in + (size_t)i * 8);
    float4 a = p[0], b = p[1];
    bf16x8 h;
    h[0] = f2bf(a.x); h[1] = f2bf(a.y); h[2] = f2bf(a.z); h[3] = f2bf(a.w);
    h[4] = f2bf(b.x); h[5] = f2bf(b.y); h[6] = f2bf(b.z); h[7] = f2bf(b.w);
    *(bf16x8*)(out + (size_t)i * 8) = h;
  }
}

// ---------------- transpose + fp32->bf16: out[n][k] = in[k][n] ----------------
__global__ void k_transpose(const float* __restrict__ in, short* __restrict__ out,
                            int K, int N) {
  __shared__ float tile[32][33];
  const int n0 = blockIdx.x * 32, k0 = blockIdx.y * 32;
  const int tx = threadIdx.x, ty = threadIdx.y;
#pragma unroll
  for (int i = 0; i < 32; i += 8)
    tile[ty + i][tx] = in[(size_t)(k0 + ty + i) * N + n0 + tx];
  __syncthreads();
#pragma unroll
  for (int i = 0; i < 32; i += 8)
    out[(size_t)(n0 + ty + i) * K + k0 + tx] = f2bf(tile[tx][ty + i]);
}

// ---------------- GEMM1: qkv = xb @ WqkvT^T + b; scatter Q(scaled)/K/V^T ----------------
__global__ __launch_bounds__(256) void k_gemm_qkv(
    const short* __restrict__ A, const short* __restrict__ Bt,
    const float* __restrict__ bias,
    short* __restrict__ qw, short* __restrict__ kw, short* __restrict__ vtg) {
  __shared__ alignas(16) short Als[128][32];
  __shared__ alignas(16) short Bls[128][32];
  const int tid = threadIdx.x, lane = tid & 63, wid = tid >> 6;
  const int wr = wid >> 1, wc = wid & 1;
  const int bm = blockIdx.x, bn = blockIdx.y;
  const int fr = lane & 15, fg = lane >> 4;
  const int arow = lane >> 2, achk = lane & 3;  // 16 rows x 4 chunks per 1KB DMA
  f32x4 acc[4][4] = {};
  const short* Ap = A + (size_t)(bm * 128) * DIMM;
  const short* Bp = Bt + (size_t)(bn * 128) * DIMM;
  for (int k0 = 0; k0 < DIMM; k0 += 32) {
    __syncthreads();
#pragma unroll
    for (int c = 0; c < 2; c++) {
      const int r0 = (wid * 2 + c) * 16;
      gload16(Ap + (size_t)(r0 + arow) * DIMM + k0 + achk * 8, &Als[r0][0]);
      gload16(Bp + (size_t)(r0 + arow) * DIMM + k0 + achk * 8, &Bls[r0][0]);
    }
    __syncthreads();
    bf16x8 af[4], bfv[4];
#pragma unroll
    for (int i = 0; i < 4; i++) {
      af[i] = *(const bf16x8*)&Als[wr * 64 + i * 16 + fr][fg * 8];
      bfv[i] = *(const bf16x8*)&Bls[wc * 64 + i * 16 + fr][fg * 8];
    }
#pragma unroll
    for (int i = 0; i < 4; i++)
#pragma unroll
      for (int j = 0; j < 4; j++)
        acc[i][j] = __builtin_amdgcn_mfma_f32_16x16x32_bf16(af[i], bfv[j], acc[i][j], 0, 0, 0);
  }
#pragma unroll
  for (int i = 0; i < 4; i++) {
    const int row0 = bm * 128 + wr * 64 + i * 16 + fg * 4;
    const int bb = row0 >> 11, s0 = row0 & 2047;
#pragma unroll
    for (int j = 0; j < 4; j++) {
      const int col = bn * 128 + wc * 64 + j * 16 + fr;
      const int h = col / 192;
      const int rem = col - h * 192;
      const int which = rem >> 6, d = rem & 63;
      const float bs = bias[col];
      if (which == 2) {
        bf16x4 pk;
#pragma unroll
        for (int r = 0; r < 4; r++) pk[r] = f2bf(acc[i][j][r] + bs);
        *(bf16x4*)&vtg[((size_t)((bb * NH + h) * HD + d)) * SEQ + s0] = pk;
      } else {
        short* dst = which == 0 ? qw : kw;
        const float scl = which == 0 ? SCQ : 1.f;
#pragma unroll
        for (int r = 0; r < 4; r++)
          dst[((size_t)((bb * NH + h) * SEQ + s0 + r)) * HD + d] =
              f2bf((acc[i][j][r] + bs) * scl);
      }
    }
  }
}

// ---------------- flash attention: 8 waves, 32 q/wave, dbuf gload_lds ----------------
// Q pre-scaled by 0.125*log2e, so P = exp2(S - m) directly.
// LDS image: tile[row][s] holds global slot s^(row&7) (16B slots) — written by
// linear-dest DMA from pre-swizzled source; frag reads XOR the slot back.
__global__ __launch_bounds__(512, 4) void k_attn(
    const short* __restrict__ qw, const short* __restrict__ kw,
    const short* __restrict__ vt, short* __restrict__ vals) {
  __shared__ alignas(16) short Kls[2][64][64];
  __shared__ alignas(16) short Vls[2][64][64];   // [d][key]
  __shared__ alignas(16) short Pls[8][16][64];   // per-wave [q][key], reused per group
  const int tid = threadIdx.x, lane = tid & 63, w = tid >> 6;
  const int fr = lane & 15, fg = lane >> 4;
  const int sw = fr & 7;

  // XCD-chunked bijective remap: nwg=512, 64 ids/XCD -> 8 heads/XCD (4MB KV = L2)
  const int flat = blockIdx.x;
  const int wrk = (flat & 7) * 64 + (flat >> 3);
  const int qt = wrk & 7, bh = wrk >> 3;

  const short* Qp = qw + (size_t)bh * SEQ * HD;
  const short* Kp = kw + (size_t)bh * SEQ * HD;
  const short* Vtp = vt + (size_t)bh * HD * SEQ;

  const int q0 = qt * 256 + w * 32;
  bf16x8 qf[2][2];
#pragma unroll
  for (int g = 0; g < 2; g++) {
    const size_t qr = (size_t)(q0 + g * 16 + fr) * HD;
    qf[g][0] = *(const bf16x8*)&Qp[qr + fg * 8];
    qf[g][1] = *(const bf16x8*)&Qp[qr + 32 + fg * 8];
  }

  f32x4 o[2][4] = {};
  float m[2] = {-1e30f, -1e30f};
  float ln[2] = {0.f, 0.f};

  // staging geometry: wave w DMAs rows w*8..w*8+7 (1KB) of K and of V
  const int srow = w * 8 + (lane >> 3);
  const int sslot = (lane & 7) ^ (srow & 7);  // pre-swizzled source slot

  int cur = 0;
  // prologue: stage tile 0
  gload16(Kp + (size_t)srow * HD + sslot * 8, &Kls[0][w * 8][0]);
  gload16(Vtp + (size_t)srow * SEQ + sslot * 8, &Vls[0][w * 8][0]);

  for (int t = 0; t < SEQ / 64; t++) {
    __syncthreads();  // drains this wave's DMA -> buf[cur] ready; prev reads done
    if (t + 1 < SEQ / 64) {
      const int kb = (t + 1) * 64;
      gload16(Kp + (size_t)(kb + srow) * HD + sslot * 8, &Kls[cur ^ 1][w * 8][0]);
      gload16(Vtp + (size_t)srow * SEQ + kb + sslot * 8, &Vls[cur ^ 1][w * 8][0]);
    }

    // S^T = K Q^T for both q-groups; lane holds q = fr, keys kt*16 + fg*4 + r
    f32x4 s[2][4];
    __builtin_amdgcn_s_setprio(1);
#pragma unroll
    for (int kt = 0; kt < 4; kt++) {
      const bf16x8 kf0 = *(const bf16x8*)&Kls[cur][kt * 16 + fr][(fg ^ sw) << 3];
      const bf16x8 kf1 = *(const bf16x8*)&Kls[cur][kt * 16 + fr][((4 + fg) ^ sw) << 3];
#pragma unroll
      for (int g = 0; g < 2; g++) {
        f32x4 z = {0.f, 0.f, 0.f, 0.f};
        z = __builtin_amdgcn_mfma_f32_16x16x32_bf16(kf0, qf[g][0], z, 0, 0, 0);
        s[g][kt] = __builtin_amdgcn_mfma_f32_16x16x32_bf16(kf1, qf[g][1], z, 0, 0, 0);
      }
    }
    __builtin_amdgcn_s_setprio(0);

    // V frags once, reused by both groups
    bf16x8 vf[2][4];
#pragma unroll
    for (int c = 0; c < 2; c++)
#pragma unroll
      for (int dt = 0; dt < 4; dt++)
        vf[c][dt] = *(const bf16x8*)&Vls[cur][dt * 16 + fr][((c * 4 + fg) ^ sw) << 3];

#pragma unroll
    for (int g = 0; g < 2; g++) {
      float mx = fmaxf(fmaxf(s[g][0][0], s[g][0][1]), fmaxf(s[g][0][2], s[g][0][3]));
      mx = fmaxf(mx, fmaxf(fmaxf(s[g][1][0], s[g][1][1]), fmaxf(s[g][1][2], s[g][1][3])));
      mx = fmaxf(mx, fmaxf(fmaxf(s[g][2][0], s[g][2][1]), fmaxf(s[g][2][2], s[g][2][3])));
      mx = fmaxf(mx, fmaxf(fmaxf(s[g][3][0], s[g][3][1]), fmaxf(s[g][3][2], s[g][3][3])));
      mx = fmaxf(mx, __shfl_xor(mx, 16));
      mx = fmaxf(mx, __shfl_xor(mx, 32));

      if (__any(mx > m[g])) {
        const float mnew = fmaxf(m[g], mx);
        const float al = exp2f(m[g] - mnew);
        m[g] = mnew;
        ln[g] *= al;
#pragma unroll
        for (int r = 0; r < 4; r++) {
          const float ar = __shfl(al, fg * 4 + r);
          o[g][0][r] *= ar; o[g][1][r] *= ar; o[g][2][r] *= ar; o[g][3][r] *= ar;
        }
      }

      float ts = 0.f;
#pragma unroll
      for (int kt = 0; kt < 4; kt++) {
        bf16x4 pk;
#pragma unroll
        for (int r = 0; r < 4; r++) {
          const float p = exp2f(s[g][kt][r] - m[g]);
          ts += p;
          pk[r] = f2bf(p);
        }
        *(bf16x4*)&Pls[w][fr][(((kt * 2 + (fg >> 1)) ^ sw) << 3) + ((fg & 1) << 2)] = pk;
      }
      ln[g] += ts;

      __builtin_amdgcn_s_setprio(1);
#pragma unroll
      for (int c = 0; c < 2; c++) {
        const bf16x8 pa = *(const bf16x8*)&Pls[w][fr][((c * 4 + fg) ^ sw) << 3];
#pragma unroll
        for (int dt = 0; dt < 4; dt++)
          o[g][dt] = __builtin_amdgcn_mfma_f32_16x16x32_bf16(pa, vf[c][dt], o[g][dt], 0, 0, 0);
      }
      __builtin_amdgcn_s_setprio(0);
    }
    cur ^= 1;
  }

  const int b = bh >> 4, h = bh & 15;
#pragma unroll
  for (int g = 0; g < 2; g++) {
    float lt = ln[g];
    lt += __shfl_xor(lt, 16);
    lt += __shfl_xor(lt, 32);
    const float inv = 1.f / lt;
#pragma unroll
    for (int r = 0; r < 4; r++) {
      const float ir = __shfl(inv, fg * 4 + r);
      const int row = q0 + g * 16 + 4 * fg + r;
      const size_t base = ((size_t)(b * SEQ + row)) * DIMM + h * HD;
#pragma unroll
      for (int dt = 0; dt < 4; dt++)
        vals[base + dt * 16 + fr] = f2bf(o[g][dt][r] * ir);
    }
  }
}

// ---------------- GEMM2: out = vals @ WoutT^T + b (fp32 out) ----------------
__global__ __launch_bounds__(256) void k_gemm_out(
    const short* __restrict__ A, const short* __restrict__ Bt,
    const float* __restrict__ bias, float* __restrict__ out) {
  __shared__ alignas(16) short Als[128][32];
  __shared__ alignas(16) short Bls[128][32];
  const int tid = threadIdx.x, lane = tid & 63, wid = tid >> 6;
  const int wr = wid >> 1, wc = wid & 1;
  const int bm = blockIdx.x, bn = blockIdx.y;
  const int fr = lane & 15, fg = lane >> 4;
  const int arow = lane >> 2, achk = lane & 3;
  f32x4 acc[4][4] = {};
  const short* Ap = A + (size_t)(bm * 128) * DIMM;
  const short* Bp = Bt + (size_t)(bn * 128) * DIMM;
  for (int k0 = 0; k0 < DIMM; k0 += 32) {
    __syncthreads();
#pragma unroll
    for (int c = 0; c < 2; c++) {
      const int r0 = (wid * 2 + c) * 16;
      gload16(Ap + (size_t)(r0 + arow) * DIMM + k0 + achk * 8, &Als[r0][0]);
      gload16(Bp + (size_t)(r0 + arow) * DIMM + k0 + achk * 8, &Bls[r0][0]);
    }
    __syncthreads();
    bf16x8 af[4], bfv[4];
#pragma unroll
    for (int i = 0; i < 4; i++) {
      af[i] = *(const bf16x8*)&Als[wr * 64 + i * 16 + fr][fg * 8];
      bfv[i] = *(const bf16x8*)&Bls[wc * 64 + i * 16 + fr][fg * 8];
    }
#pragma unroll
    for (int i = 0; i < 4; i++)
#pragma unroll
      for (int j = 0; j < 4; j++)
        acc[i][j] = __builtin_amdgcn_mfma_f32_16x16x32_bf16(af[i], bfv[j], acc[i][j], 0, 0, 0);
  }
#pragma unroll
  for (int i = 0; i < 4; i++) {
    const int row0 = bm * 128 + wr * 64 + i * 16 + fg * 4;
#pragma unroll
    for (int j = 0; j < 4; j++) {
      const int col = bn * 128 + wc * 64 + j * 16 + fr;
      const float bs = bias[col];
#pragma unroll
      for (int r = 0; r < 4; r++)
        out[(size_t)(row0 + r) * DIMM + col] = acc[i][j][r] + bs;
    }
  }
}

extern "C" void kernel_launch(void* const* d_in, const int* in_sizes, int n_in,
                              void* d_out, int out_size, void* d_ws, size_t ws_size,
                              hipStream_t stream) {
  (void)in_sizes; (void)n_in; (void)out_size;
  const float* x = (const float*)d_in[0];
  const float* Wqkv = (const float*)d_in[1];
  const float* bqkv = (const float*)d_in[2];
  const float* Wout = (const float*)d_in[3];
  const float* bout = (const float*)d_in[4];
  float* out = (float*)d_out;

  char* ws = (char*)d_ws;
  const size_t sz_wq = (size_t)3 * DIMM * DIMM * 2;
  const size_t sz_wo = (size_t)DIMM * DIMM * 2;
  const size_t sz_m = (size_t)MTOT * DIMM * 2;
  const size_t off_wq = 0;
  const size_t off_wo = off_wq + sz_wq;
  const size_t off_q = off_wo + sz_wo;
  const size_t off_k = off_q + sz_m;
  const size_t off_vt = off_k + sz_m;
  const size_t off_vals = off_vt + sz_m;  // doubles as xb
  const size_t need = off_vals + sz_m;
  if (ws_size < need) return;

  short* WqT = (short*)(ws + off_wq);
  short* WoT = (short*)(ws + off_wo);
  short* qws = (short*)(ws + off_q);
  short* kws = (short*)(ws + off_k);
  short* vtg = (short*)(ws + off_vt);
  short* xb = (short*)(ws + off_vals);
  short* valsws = (short*)(ws + off_vals);

  k_cvt<<<2048, 256, 0, stream>>>(x, xb, MTOT * DIMM / 8);
  k_transpose<<<dim3(3 * DIMM / 32, DIMM / 32), dim3(32, 8), 0, stream>>>(Wqkv, WqT, DIMM, 3 * DIMM);
  k_transpose<<<dim3(DIMM / 32, DIMM / 32), dim3(32, 8), 0, stream>>>(Wout, WoT, DIMM, DIMM);
  k_gemm_qkv<<<dim3(MTOT / 128, 3 * DIMM / 128), 256, 0, stream>>>(xb, WqT, bqkv, qws, kws, vtg);
  k_attn<<<512, 512, 0, stream>>>(qws, kws, vtg, valsws);
  k_gemm_out<<<dim3(MTOT / 128, DIMM / 128), 256, 0, stream>>>(valsws, WoT, bout, out);
}